// Round 5
// baseline (107.764 us; speedup 1.0000x reference)
//
#include <hip/hip_runtime.h>
#include <hip/hip_fp16.h>

// out[b,o] = sum_k x[b, conn[o,k]] * w[o,k]
// B=1024, In=8192, O=8192, K=32.
//
// R5: VALU diet. R4's perm+fdot2 path cost ~20 VALU per 4 gathers (perms
// pair same-row halves across gathers for f32-acc dot2). v_pk_fma_f16
// needs no perms: lds g.x IS half2(row0,row1). Weights pre-duplicated
// half2(w,w) at repack into a second stream. Inner j-iter: 4 unpack +
// 8 pk_fma + 4 ds_read_b64 + 2 vmem. f16 accumulation split into two
// 16-step chains (a/b), combined in f32 at epilogue for precision.
// x staging unchanged: 4 rows transposed in LDS as f16x4; one
// ds_read_b64 serves 4 batch rows per gather index. 1024-thr blocks,
// 2/CU co-resident (128 KiB LDS), 8 waves/SIMD (HW cap).

constexpr int IN_F    = 8192;
constexpr int OUT_F   = 8192;
constexpr int KPER    = 32;
constexpr int BATCH   = 1024;
constexpr int ROWS    = 4;         // batch rows per block
constexpr int THREADS = 1024;      // 16 waves
constexpr int OHALF   = OUT_F / 2; // outputs per block
constexpr size_t OFFS_BYTES = (size_t)OUT_F * (KPER / 4) * 8;   // 512 KiB
constexpr size_t WDUP_BYTES = (size_t)OUT_F * (KPER / 4) * 16;  // 1 MiB
constexpr size_t PK_BYTES   = OFFS_BYTES + WDUP_BYTES;

// offs[j][o] = uint2{ (c0*8)|(c1*8<<16), (c2*8)|(c3*8<<16) }  (LDS byte offs)
// wdup[j][o] = uint4{ h2(w0,w0), h2(w1,w1), h2(w2,w2), h2(w3,w3) }
__global__ __launch_bounds__(256)
void psl_repack(const int* __restrict__ conn, const float* __restrict__ w,
                uint2* __restrict__ offs, uint4* __restrict__ wdup) {
    const int t = blockIdx.x * 256 + threadIdx.x;  // OUT_F * 8 threads
    const int j = t >> 13;          // 0..7
    const int o = t & (OUT_F - 1);
    const int base = o * KPER + j * 4;
    const int4   ci = *reinterpret_cast<const int4*>(conn + base);
    const float4 wj = *reinterpret_cast<const float4*>(w + base);

    uint2 ov;
    ov.x = ((unsigned)ci.x << 3) | ((unsigned)ci.y << 19);
    ov.y = ((unsigned)ci.z << 3) | ((unsigned)ci.w << 19);
    offs[(size_t)j * OUT_F + o] = ov;

    __half2 d0 = __floats2half2_rn(wj.x, wj.x);
    __half2 d1 = __floats2half2_rn(wj.y, wj.y);
    __half2 d2 = __floats2half2_rn(wj.z, wj.z);
    __half2 d3 = __floats2half2_rn(wj.w, wj.w);
    uint4 wv;
    wv.x = *reinterpret_cast<unsigned*>(&d0);
    wv.y = *reinterpret_cast<unsigned*>(&d1);
    wv.z = *reinterpret_cast<unsigned*>(&d2);
    wv.w = *reinterpret_cast<unsigned*>(&d3);
    wdup[(size_t)j * OUT_F + o] = wv;
}

__device__ __forceinline__ __half2 u2h2(unsigned u) {
    return __builtin_bit_cast(__half2, u);
}

__global__ __launch_bounds__(THREADS, 8)
void psl_main(const float* __restrict__ x,
              const uint2* __restrict__ offs,
              const uint4* __restrict__ wdup,
              float* __restrict__ out) {
    __shared__ uint2 lds_x[IN_F];  // 64 KiB: [col] -> 4 batch rows as f16

    const int tid = threadIdx.x;
    const int bt  = blockIdx.x >> 1;      // batch tile
    const int oh  = blockIdx.x & 1;       // output half
    const long b0 = (long)bt * ROWS;

    const float* xr0 = x + (b0 + 0) * IN_F;
    const float* xr1 = x + (b0 + 1) * IN_F;
    const float* xr2 = x + (b0 + 2) * IN_F;
    const float* xr3 = x + (b0 + 3) * IN_F;

    for (int c = tid; c < IN_F; c += THREADS) {
        __half2 h01 = __floats2half2_rn(xr0[c], xr1[c]);
        __half2 h23 = __floats2half2_rn(xr2[c], xr3[c]);
        uint2 pkx;
        pkx.x = *reinterpret_cast<unsigned*>(&h01);
        pkx.y = *reinterpret_cast<unsigned*>(&h23);
        lds_x[c] = pkx;
    }
    __syncthreads();

    float* or0 = out + (b0 + 0) * OUT_F;
    float* or1 = out + (b0 + 1) * OUT_F;
    float* or2 = out + (b0 + 2) * OUT_F;
    float* or3 = out + (b0 + 3) * OUT_F;

    const int obase = oh * OHALF;
    const char* ldsb = reinterpret_cast<const char*>(lds_x);

    for (int jj = 0; jj < OHALF / THREADS; ++jj) {
        const int o = obase + jj * THREADS + tid;
        const uint2* op = offs + o;
        const uint4* wp = wdup + o;

        __half2 z = __float2half2_rn(0.f);
        __half2 a01a = z, a23a = z, a01b = z, a23b = z;

#pragma unroll 2
        for (int j = 0; j < KPER / 4; ++j) {
            const uint2 ov = op[(size_t)j * OUT_F];   // lane-contiguous 8 B
            const uint4 wv = wp[(size_t)j * OUT_F];   // lane-contiguous 16 B
            const unsigned off0 = ov.x & 0xFFFFu, off1 = ov.x >> 16;
            const unsigned off2 = ov.y & 0xFFFFu, off3 = ov.y >> 16;
            const uint2 g0 = *reinterpret_cast<const uint2*>(ldsb + off0);
            const uint2 g1 = *reinterpret_cast<const uint2*>(ldsb + off1);
            const uint2 g2 = *reinterpret_cast<const uint2*>(ldsb + off2);
            const uint2 g3 = *reinterpret_cast<const uint2*>(ldsb + off3);

            a01a = __hfma2(u2h2(g0.x), u2h2(wv.x), a01a);
            a23a = __hfma2(u2h2(g0.y), u2h2(wv.x), a23a);
            a01b = __hfma2(u2h2(g1.x), u2h2(wv.y), a01b);
            a23b = __hfma2(u2h2(g1.y), u2h2(wv.y), a23b);
            a01a = __hfma2(u2h2(g2.x), u2h2(wv.z), a01a);
            a23a = __hfma2(u2h2(g2.y), u2h2(wv.z), a23a);
            a01b = __hfma2(u2h2(g3.x), u2h2(wv.w), a01b);
            a23b = __hfma2(u2h2(g3.y), u2h2(wv.w), a23b);
        }

        const float2 r01a = __half22float2(a01a);
        const float2 r01b = __half22float2(a01b);
        const float2 r23a = __half22float2(a23a);
        const float2 r23b = __half22float2(a23b);
        or0[o] = r01a.x + r01b.x;
        or1[o] = r01a.y + r01b.y;
        or2[o] = r23a.x + r23b.x;
        or3[o] = r23a.y + r23b.y;
    }
}

// ---- fallback (no-ws path, R1 structure) ----
__global__ __launch_bounds__(512, 4)
void psl_fallback(const float* __restrict__ x, const int* __restrict__ conn,
                  const float* __restrict__ w, float* __restrict__ out) {
    __shared__ uint2 lds_x[IN_F];
    const int tid = threadIdx.x;
    const int bt  = blockIdx.x >> 1;
    const int oh  = blockIdx.x & 1;
    const long b0 = (long)bt * ROWS;
    const float* xr0 = x + (b0 + 0) * IN_F;
    const float* xr1 = x + (b0 + 1) * IN_F;
    const float* xr2 = x + (b0 + 2) * IN_F;
    const float* xr3 = x + (b0 + 3) * IN_F;
    for (int c = tid; c < IN_F; c += 512) {
        __half2 h01 = __floats2half2_rn(xr0[c], xr1[c]);
        __half2 h23 = __floats2half2_rn(xr2[c], xr3[c]);
        uint2 pkx;
        pkx.x = *reinterpret_cast<unsigned*>(&h01);
        pkx.y = *reinterpret_cast<unsigned*>(&h23);
        lds_x[c] = pkx;
    }
    __syncthreads();
    float* or0 = out + (b0 + 0) * OUT_F;
    float* or1 = out + (b0 + 1) * OUT_F;
    float* or2 = out + (b0 + 2) * OUT_F;
    float* or3 = out + (b0 + 3) * OUT_F;
    const int obase = oh * OHALF;
    for (int j = 0; j < OHALF / 512; ++j) {
        const int o = obase + j * 512 + tid;
        const int4*   c4 = reinterpret_cast<const int4*>(conn + (size_t)o * KPER);
        const float4* w4 = reinterpret_cast<const float4*>(w + (size_t)o * KPER);
        float a0 = 0.f, a1 = 0.f, a2 = 0.f, a3 = 0.f;
#define GACC(IDX, WT)                                              \
        {                                                          \
            uint2 v = lds_x[(IDX)];                                \
            __half2 h01 = *reinterpret_cast<__half2*>(&v.x);       \
            __half2 h23 = *reinterpret_cast<__half2*>(&v.y);       \
            float2 f01 = __half22float2(h01);                      \
            float2 f23 = __half22float2(h23);                      \
            a0 = fmaf(f01.x, (WT), a0);                            \
            a1 = fmaf(f01.y, (WT), a1);                            \
            a2 = fmaf(f23.x, (WT), a2);                            \
            a3 = fmaf(f23.y, (WT), a3);                            \
        }
#pragma unroll
        for (int jj = 0; jj < KPER / 4; ++jj) {
            const int4   ci = c4[jj];
            const float4 wj = w4[jj];
            GACC(ci.x, wj.x);
            GACC(ci.y, wj.y);
            GACC(ci.z, wj.z);
            GACC(ci.w, wj.w);
        }
#undef GACC
        or0[o] = a0;
        or1[o] = a1;
        or2[o] = a2;
        or3[o] = a3;
    }
}

extern "C" void kernel_launch(void* const* d_in, const int* in_sizes, int n_in,
                              void* d_out, int out_size, void* d_ws, size_t ws_size,
                              hipStream_t stream) {
    const float* x    = (const float*)d_in[0];
    const int*   conn = (const int*)d_in[1];
    const float* w    = (const float*)d_in[2];
    float*       out  = (float*)d_out;

    if (ws_size >= PK_BYTES) {
        uint2* offs = (uint2*)d_ws;
        uint4* wd   = (uint4*)((char*)d_ws + OFFS_BYTES);
        psl_repack<<<dim3(OUT_F * (KPER / 4) / 256), 256, 0, stream>>>(conn, w, offs, wd);
        psl_main<<<dim3((BATCH / ROWS) * 2), THREADS, 0, stream>>>(x, offs, wd, out);
    } else {
        psl_fallback<<<dim3((BATCH / ROWS) * 2), 512, 0, stream>>>(x, conn, w, out);
    }
}

// Round 6
// 102.176 us; speedup vs baseline: 1.0547x; 1.0547x over previous
//
#include <hip/hip_runtime.h>
#include <hip/hip_fp16.h>

// out[b,o] = sum_k x[b, conn[o,k]] * w[o,k]
// B=1024, In=8192, O=8192, K=32.
//
// R6: amortize over 8 batch rows. x[8 rows] transposed in LDS as f16x8
// (uint4 per column, 128 KiB -- gfx950 allows 160 KiB/workgroup). One
// ds_read_b128 serves 8 rows per gather index (half the LDS instrs of
// R4/R5). pk stream (combined: 4 u16 idx + 4 f16 w = 16 B per k-quad,
// 128 B/output) is amortized over 8 rows -> 0.5 MB/CU from L2 (was 1).
// Inner math: v_pk_fma_f16 with weight broadcast (__half2half2 ->
// op_sel), two 16-step f16 chains combined in f32 at epilogue.
// grid = 128 batch-tiles x 2 output-halves = 256 blocks = 1/CU.

constexpr int IN_F    = 8192;
constexpr int OUT_F   = 8192;
constexpr int KPER    = 32;
constexpr int BATCH   = 1024;
constexpr int ROWS    = 8;         // batch rows per block
constexpr int THREADS = 1024;      // 16 waves, 4/SIMD (1 block/CU)
constexpr int OHALF   = OUT_F / 2; // outputs per block
constexpr size_t PK_BYTES = (size_t)OUT_F * (KPER / 4) * 16;  // 1 MiB

// pk[j][o] (j=k/4): uint4 { i0|i1<<16, i2|i3<<16, h2(w0,w1), h2(w2,w3) }
__global__ __launch_bounds__(256)
void psl_repack(const int* __restrict__ conn, const float* __restrict__ w,
                uint4* __restrict__ pk) {
    const int t = blockIdx.x * 256 + threadIdx.x;  // OUT_F * 8 threads
    const int j = t >> 13;          // 0..7
    const int o = t & (OUT_F - 1);
    const int base = o * KPER + j * 4;
    const int4   ci = *reinterpret_cast<const int4*>(conn + base);
    const float4 wj = *reinterpret_cast<const float4*>(w + base);
    uint4 v;
    v.x = (unsigned)ci.x | ((unsigned)ci.y << 16);
    v.y = (unsigned)ci.z | ((unsigned)ci.w << 16);
    __half2 w01 = __floats2half2_rn(wj.x, wj.y);
    __half2 w23 = __floats2half2_rn(wj.z, wj.w);
    v.z = *reinterpret_cast<unsigned*>(&w01);
    v.w = *reinterpret_cast<unsigned*>(&w23);
    pk[(size_t)j * OUT_F + o] = v;
}

__device__ __forceinline__ __half2 u2h2(unsigned u) {
    return __builtin_bit_cast(__half2, u);
}
__device__ __forceinline__ unsigned packh2(float a, float b) {
    __half2 h = __floats2half2_rn(a, b);
    return *reinterpret_cast<unsigned*>(&h);
}

__global__ __launch_bounds__(THREADS, 4)
void psl_main(const float* __restrict__ x, const uint4* __restrict__ pk,
              float* __restrict__ out) {
    __shared__ uint4 lds_x[IN_F];  // 128 KiB: [col] -> 8 batch rows as f16

    const int tid = threadIdx.x;
    const int bt  = blockIdx.x >> 1;      // batch tile
    const int oh  = blockIdx.x & 1;       // output half
    const long b0 = (long)bt * ROWS;

    const float* xr = x + b0 * IN_F;

    // Stage: 8 coalesced row sweeps, pack 8 rows -> 16 B, ds_write_b128
    // at lane-stride 16 B (minimum-conflict pattern).
    for (int c = tid; c < IN_F; c += THREADS) {
        uint4 pkx;
        pkx.x = packh2(xr[0 * IN_F + c], xr[1 * IN_F + c]);
        pkx.y = packh2(xr[2 * IN_F + c], xr[3 * IN_F + c]);
        pkx.z = packh2(xr[4 * IN_F + c], xr[5 * IN_F + c]);
        pkx.w = packh2(xr[6 * IN_F + c], xr[7 * IN_F + c]);
        lds_x[c] = pkx;
    }
    __syncthreads();

    float* outb = out + b0 * OUT_F;
    const int obase = oh * OHALF;

    for (int jj = 0; jj < OHALF / THREADS; ++jj) {
        const int o = obase + jj * THREADS + tid;
        const uint4* pkrow = pk + o;

        __half2 z = __float2half2_rn(0.f);
        __half2 a01 = z, a23 = z, a45 = z, a67 = z;   // chain a
        __half2 b01 = z, b23 = z, b45 = z, b67 = z;   // chain b

#pragma unroll
        for (int j = 0; j < KPER / 4; ++j) {
            const uint4 v = pkrow[(size_t)j * OUT_F];  // lane-contiguous 16 B
            const unsigned i0 = v.x & 0xFFFFu, i1 = v.x >> 16;
            const unsigned i2 = v.y & 0xFFFFu, i3 = v.y >> 16;
            const uint4 g0 = lds_x[i0];
            const uint4 g1 = lds_x[i1];
            const uint4 g2 = lds_x[i2];
            const uint4 g3 = lds_x[i3];
            const __half2 w01 = u2h2(v.z), w23 = u2h2(v.w);
            const __half2 wd0 = __half2half2(__low2half(w01));
            const __half2 wd1 = __half2half2(__high2half(w01));
            const __half2 wd2 = __half2half2(__low2half(w23));
            const __half2 wd3 = __half2half2(__high2half(w23));

            a01 = __hfma2(u2h2(g0.x), wd0, a01);
            a23 = __hfma2(u2h2(g0.y), wd0, a23);
            a45 = __hfma2(u2h2(g0.z), wd0, a45);
            a67 = __hfma2(u2h2(g0.w), wd0, a67);
            b01 = __hfma2(u2h2(g1.x), wd1, b01);
            b23 = __hfma2(u2h2(g1.y), wd1, b23);
            b45 = __hfma2(u2h2(g1.z), wd1, b45);
            b67 = __hfma2(u2h2(g1.w), wd1, b67);
            a01 = __hfma2(u2h2(g2.x), wd2, a01);
            a23 = __hfma2(u2h2(g2.y), wd2, a23);
            a45 = __hfma2(u2h2(g2.z), wd2, a45);
            a67 = __hfma2(u2h2(g2.w), wd2, a67);
            b01 = __hfma2(u2h2(g3.x), wd3, b01);
            b23 = __hfma2(u2h2(g3.y), wd3, b23);
            b45 = __hfma2(u2h2(g3.z), wd3, b45);
            b67 = __hfma2(u2h2(g3.w), wd3, b67);
        }

        const float2 r01 = __half22float2(a01), s01 = __half22float2(b01);
        const float2 r23 = __half22float2(a23), s23 = __half22float2(b23);
        const float2 r45 = __half22float2(a45), s45 = __half22float2(b45);
        const float2 r67 = __half22float2(a67), s67 = __half22float2(b67);
        outb[0 * OUT_F + o] = r01.x + s01.x;
        outb[1 * OUT_F + o] = r01.y + s01.y;
        outb[2 * OUT_F + o] = r23.x + s23.x;
        outb[3 * OUT_F + o] = r23.y + s23.y;
        outb[4 * OUT_F + o] = r45.x + s45.x;
        outb[5 * OUT_F + o] = r45.y + s45.y;
        outb[6 * OUT_F + o] = r67.x + s67.x;
        outb[7 * OUT_F + o] = r67.y + s67.y;
    }
}

// ---- fallback (no-ws path, R1 structure, 4 rows / 64 KiB) ----
__global__ __launch_bounds__(512, 4)
void psl_fallback(const float* __restrict__ x, const int* __restrict__ conn,
                  const float* __restrict__ w, float* __restrict__ out) {
    __shared__ uint2 lds_x[IN_F];
    const int tid = threadIdx.x;
    const int bt  = blockIdx.x >> 1;
    const int oh  = blockIdx.x & 1;
    const long b0 = (long)bt * 4;
    const float* xr0 = x + (b0 + 0) * IN_F;
    const float* xr1 = x + (b0 + 1) * IN_F;
    const float* xr2 = x + (b0 + 2) * IN_F;
    const float* xr3 = x + (b0 + 3) * IN_F;
    for (int c = tid; c < IN_F; c += 512) {
        uint2 pkx;
        pkx.x = packh2(xr0[c], xr1[c]);
        pkx.y = packh2(xr2[c], xr3[c]);
        lds_x[c] = pkx;
    }
    __syncthreads();
    float* or0 = out + (b0 + 0) * OUT_F;
    float* or1 = out + (b0 + 1) * OUT_F;
    float* or2 = out + (b0 + 2) * OUT_F;
    float* or3 = out + (b0 + 3) * OUT_F;
    const int obase = oh * OHALF;
    for (int j = 0; j < OHALF / 512; ++j) {
        const int o = obase + j * 512 + tid;
        const int4*   c4 = reinterpret_cast<const int4*>(conn + (size_t)o * KPER);
        const float4* w4 = reinterpret_cast<const float4*>(w + (size_t)o * KPER);
        float a0 = 0.f, a1 = 0.f, a2 = 0.f, a3 = 0.f;
#define GACC(IDX, WT)                                              \
        {                                                          \
            uint2 v = lds_x[(IDX)];                                \
            __half2 h01 = *reinterpret_cast<__half2*>(&v.x);       \
            __half2 h23 = *reinterpret_cast<__half2*>(&v.y);       \
            float2 f01 = __half22float2(h01);                      \
            float2 f23 = __half22float2(h23);                      \
            a0 = fmaf(f01.x, (WT), a0);                            \
            a1 = fmaf(f01.y, (WT), a1);                            \
            a2 = fmaf(f23.x, (WT), a2);                            \
            a3 = fmaf(f23.y, (WT), a3);                            \
        }
#pragma unroll
        for (int jj = 0; jj < KPER / 4; ++jj) {
            const int4   ci = c4[jj];
            const float4 wj = w4[jj];
            GACC(ci.x, wj.x);
            GACC(ci.y, wj.y);
            GACC(ci.z, wj.z);
            GACC(ci.w, wj.w);
        }
#undef GACC
        or0[o] = a0;
        or1[o] = a1;
        or2[o] = a2;
        or3[o] = a3;
    }
}

extern "C" void kernel_launch(void* const* d_in, const int* in_sizes, int n_in,
                              void* d_out, int out_size, void* d_ws, size_t ws_size,
                              hipStream_t stream) {
    const float* x    = (const float*)d_in[0];
    const int*   conn = (const int*)d_in[1];
    const float* w    = (const float*)d_in[2];
    float*       out  = (float*)d_out;

    if (ws_size >= PK_BYTES) {
        uint4* pk = (uint4*)d_ws;
        psl_repack<<<dim3(OUT_F * (KPER / 4) / 256), 256, 0, stream>>>(conn, w, pk);
        psl_main<<<dim3((BATCH / ROWS) * 2), THREADS, 0, stream>>>(x, pk, out);
    } else {
        psl_fallback<<<dim3((BATCH / 4) * 2), 512, 0, stream>>>(x, conn, w, out);
    }
}

// Round 7
// 100.397 us; speedup vs baseline: 1.0734x; 1.0177x over previous
//
#include <hip/hip_runtime.h>
#include <hip/hip_fp16.h>

// out[b,o] = sum_k x[b, conn[o,k]] * w[o,k]
// B=1024, In=8192, O=8192, K=32.
//
// R7: R6 (8 rows in LDS as f16x8, one ds_read_b128 serves 8 rows/gather)
// + XCD-aware sibling pairing. R6's regression vs prediction was the
// serial staging burst: 1 block/CU reads 256 KB fp32 x pre-barrier at
// HBM rate (~11 us, nothing to overlap). The two blocks sharing a batch
// tile (output halves) now get blockIdx differing by 8 so the i%8
// round-robin XCD mapping co-locates them: their identical x reads merge
// in the XCD's L2 -> staging at L2 BW (~2 us) and x is fetched from HBM
// once device-wide (32 MB not 64).
//   bt = (i>>4)*8 + (i&7), oh = (i>>3)&1   (grid 256)

constexpr int IN_F    = 8192;
constexpr int OUT_F   = 8192;
constexpr int KPER    = 32;
constexpr int BATCH   = 1024;
constexpr int ROWS    = 8;         // batch rows per block
constexpr int THREADS = 1024;      // 16 waves, 1 block/CU
constexpr int OHALF   = OUT_F / 2; // outputs per block
constexpr size_t PK_BYTES = (size_t)OUT_F * (KPER / 4) * 16;  // 1 MiB

// pk[j][o] (j=k/4): uint4 { i0|i1<<16, i2|i3<<16, h2(w0,w1), h2(w2,w3) }
__global__ __launch_bounds__(256)
void psl_repack(const int* __restrict__ conn, const float* __restrict__ w,
                uint4* __restrict__ pk) {
    const int t = blockIdx.x * 256 + threadIdx.x;  // OUT_F * 8 threads
    const int j = t >> 13;          // 0..7
    const int o = t & (OUT_F - 1);
    const int base = o * KPER + j * 4;
    const int4   ci = *reinterpret_cast<const int4*>(conn + base);
    const float4 wj = *reinterpret_cast<const float4*>(w + base);
    uint4 v;
    v.x = (unsigned)ci.x | ((unsigned)ci.y << 16);
    v.y = (unsigned)ci.z | ((unsigned)ci.w << 16);
    __half2 w01 = __floats2half2_rn(wj.x, wj.y);
    __half2 w23 = __floats2half2_rn(wj.z, wj.w);
    v.z = *reinterpret_cast<unsigned*>(&w01);
    v.w = *reinterpret_cast<unsigned*>(&w23);
    pk[(size_t)j * OUT_F + o] = v;
}

__device__ __forceinline__ __half2 u2h2(unsigned u) {
    return __builtin_bit_cast(__half2, u);
}
__device__ __forceinline__ unsigned packh2(float a, float b) {
    __half2 h = __floats2half2_rn(a, b);
    return *reinterpret_cast<unsigned*>(&h);
}

__global__ __launch_bounds__(THREADS, 4)
void psl_main(const float* __restrict__ x, const uint4* __restrict__ pk,
              float* __restrict__ out) {
    __shared__ uint4 lds_x[IN_F];  // 128 KiB: [col] -> 8 batch rows as f16

    const int tid = threadIdx.x;
    const int i   = blockIdx.x;
    const int bt  = ((i >> 4) << 3) | (i & 7);   // batch tile (0..127)
    const int oh  = (i >> 3) & 1;                // output half
    const long b0 = (long)bt * ROWS;

    const float* xr = x + b0 * IN_F;

    // Stage: 8 independent coalesced row reads per column, pack to 16 B,
    // ds_write_b128 at lane-stride 16 B (conflict-free).
    for (int c = tid; c < IN_F; c += THREADS) {
        float r0 = xr[0 * IN_F + c];
        float r1 = xr[1 * IN_F + c];
        float r2 = xr[2 * IN_F + c];
        float r3 = xr[3 * IN_F + c];
        float r4 = xr[4 * IN_F + c];
        float r5 = xr[5 * IN_F + c];
        float r6 = xr[6 * IN_F + c];
        float r7 = xr[7 * IN_F + c];
        uint4 pkx;
        pkx.x = packh2(r0, r1);
        pkx.y = packh2(r2, r3);
        pkx.z = packh2(r4, r5);
        pkx.w = packh2(r6, r7);
        lds_x[c] = pkx;
    }
    __syncthreads();

    float* outb = out + b0 * OUT_F;
    const int obase = oh * OHALF;

    for (int jj = 0; jj < OHALF / THREADS; ++jj) {
        const int o = obase + jj * THREADS + tid;
        const uint4* pkrow = pk + o;

        __half2 z = __float2half2_rn(0.f);
        __half2 a01 = z, a23 = z, a45 = z, a67 = z;   // chain a
        __half2 b01 = z, b23 = z, b45 = z, b67 = z;   // chain b

#pragma unroll
        for (int j = 0; j < KPER / 4; ++j) {
            const uint4 v = pkrow[(size_t)j * OUT_F];  // lane-contiguous 16 B
            const unsigned i0 = v.x & 0xFFFFu, i1 = v.x >> 16;
            const unsigned i2 = v.y & 0xFFFFu, i3 = v.y >> 16;
            const uint4 g0 = lds_x[i0];
            const uint4 g1 = lds_x[i1];
            const uint4 g2 = lds_x[i2];
            const uint4 g3 = lds_x[i3];
            const __half2 w01 = u2h2(v.z), w23 = u2h2(v.w);
            const __half2 wd0 = __half2half2(__low2half(w01));
            const __half2 wd1 = __half2half2(__high2half(w01));
            const __half2 wd2 = __half2half2(__low2half(w23));
            const __half2 wd3 = __half2half2(__high2half(w23));

            a01 = __hfma2(u2h2(g0.x), wd0, a01);
            a23 = __hfma2(u2h2(g0.y), wd0, a23);
            a45 = __hfma2(u2h2(g0.z), wd0, a45);
            a67 = __hfma2(u2h2(g0.w), wd0, a67);
            b01 = __hfma2(u2h2(g1.x), wd1, b01);
            b23 = __hfma2(u2h2(g1.y), wd1, b23);
            b45 = __hfma2(u2h2(g1.z), wd1, b45);
            b67 = __hfma2(u2h2(g1.w), wd1, b67);
            a01 = __hfma2(u2h2(g2.x), wd2, a01);
            a23 = __hfma2(u2h2(g2.y), wd2, a23);
            a45 = __hfma2(u2h2(g2.z), wd2, a45);
            a67 = __hfma2(u2h2(g2.w), wd2, a67);
            b01 = __hfma2(u2h2(g3.x), wd3, b01);
            b23 = __hfma2(u2h2(g3.y), wd3, b23);
            b45 = __hfma2(u2h2(g3.z), wd3, b45);
            b67 = __hfma2(u2h2(g3.w), wd3, b67);
        }

        const float2 r01 = __half22float2(a01), s01 = __half22float2(b01);
        const float2 r23 = __half22float2(a23), s23 = __half22float2(b23);
        const float2 r45 = __half22float2(a45), s45 = __half22float2(b45);
        const float2 r67 = __half22float2(a67), s67 = __half22float2(b67);
        outb[0 * OUT_F + o] = r01.x + s01.x;
        outb[1 * OUT_F + o] = r01.y + s01.y;
        outb[2 * OUT_F + o] = r23.x + s23.x;
        outb[3 * OUT_F + o] = r23.y + s23.y;
        outb[4 * OUT_F + o] = r45.x + s45.x;
        outb[5 * OUT_F + o] = r45.y + s45.y;
        outb[6 * OUT_F + o] = r67.x + s67.x;
        outb[7 * OUT_F + o] = r67.y + s67.y;
    }
}

// ---- fallback (no-ws path, R1 structure, 4 rows / 64 KiB) ----
__global__ __launch_bounds__(512, 4)
void psl_fallback(const float* __restrict__ x, const int* __restrict__ conn,
                  const float* __restrict__ w, float* __restrict__ out) {
    __shared__ uint2 lds_x[IN_F];
    const int tid = threadIdx.x;
    const int bt  = blockIdx.x >> 1;
    const int oh  = blockIdx.x & 1;
    const long b0 = (long)bt * 4;
    const float* xr0 = x + (b0 + 0) * IN_F;
    const float* xr1 = x + (b0 + 1) * IN_F;
    const float* xr2 = x + (b0 + 2) * IN_F;
    const float* xr3 = x + (b0 + 3) * IN_F;
    for (int c = tid; c < IN_F; c += 512) {
        uint2 pkx;
        pkx.x = packh2(xr0[c], xr1[c]);
        pkx.y = packh2(xr2[c], xr3[c]);
        lds_x[c] = pkx;
    }
    __syncthreads();
    float* or0 = out + (b0 + 0) * OUT_F;
    float* or1 = out + (b0 + 1) * OUT_F;
    float* or2 = out + (b0 + 2) * OUT_F;
    float* or3 = out + (b0 + 3) * OUT_F;
    const int obase = oh * OHALF;
    for (int j = 0; j < OHALF / 512; ++j) {
        const int o = obase + j * 512 + tid;
        const int4*   c4 = reinterpret_cast<const int4*>(conn + (size_t)o * KPER);
        const float4* w4 = reinterpret_cast<const float4*>(w + (size_t)o * KPER);
        float a0 = 0.f, a1 = 0.f, a2 = 0.f, a3 = 0.f;
#define GACC(IDX, WT)                                              \
        {                                                          \
            uint2 v = lds_x[(IDX)];                                \
            __half2 h01 = *reinterpret_cast<__half2*>(&v.x);       \
            __half2 h23 = *reinterpret_cast<__half2*>(&v.y);       \
            float2 f01 = __half22float2(h01);                      \
            float2 f23 = __half22float2(h23);                      \
            a0 = fmaf(f01.x, (WT), a0);                            \
            a1 = fmaf(f01.y, (WT), a1);                            \
            a2 = fmaf(f23.x, (WT), a2);                            \
            a3 = fmaf(f23.y, (WT), a3);                            \
        }
#pragma unroll
        for (int jj = 0; jj < KPER / 4; ++jj) {
            const int4   ci = c4[jj];
            const float4 wj = w4[jj];
            GACC(ci.x, wj.x);
            GACC(ci.y, wj.y);
            GACC(ci.z, wj.z);
            GACC(ci.w, wj.w);
        }
#undef GACC
        or0[o] = a0;
        or1[o] = a1;
        or2[o] = a2;
        or3[o] = a3;
    }
}

extern "C" void kernel_launch(void* const* d_in, const int* in_sizes, int n_in,
                              void* d_out, int out_size, void* d_ws, size_t ws_size,
                              hipStream_t stream) {
    const float* x    = (const float*)d_in[0];
    const int*   conn = (const int*)d_in[1];
    const float* w    = (const float*)d_in[2];
    float*       out  = (float*)d_out;

    if (ws_size >= PK_BYTES) {
        uint4* pk = (uint4*)d_ws;
        psl_repack<<<dim3(OUT_F * (KPER / 4) / 256), 256, 0, stream>>>(conn, w, pk);
        psl_main<<<dim3((BATCH / ROWS) * 2), THREADS, 0, stream>>>(x, pk, out);
    } else {
        psl_fallback<<<dim3((BATCH / 4) * 2), 512, 0, stream>>>(x, conn, w, out);
    }
}